// Round 5
// baseline (228.268 us; speedup 1.0000x reference)
//
#include <hip/hip_runtime.h>

// ---------------------------------------------------------------------------
// sxsGCN: h=[B=128,N=4096,3]; 3x { relu((adj@h)@W+b) }; then FC 12288->54->4096
// bf16 MFMA GEMMs adj[4096x4096] @ H[4096 x 512].
// R9: packed-B direct-to-reg + 128x64, 1 blk/CU: latency-serialized, 41us.
// R10: depth-3 counted vmcnt(16) pipeline: ~36us/gemm (1 blk/CU lockstep).
// R11: 64x64 tiles, 512 blocks, 2 blk/CU: 225us total (PASS).
// R12: cooperative mega-kernel: FAIL (grid.sync unreliable under harness /
//   cross-XCD visibility; output inflated ~264x). REVERTED.
// R13: barrier-free GEMM. A is our own tensor -> pre-pack adjB in A-frag
//   order [rb][ka][lane][8] (mirror of B pack; delivers identical elements
//   to the old LDS path: row=rb*16+(lane&15), k=ka*32+(lane>>4)*8+j).
//   K-loop = 8 coalesced 1KB reg loads + 16 MFMA per wave-step; NO LDS, no
//   barriers, no vmcnt asm; waves free-run, compiler pipelines (unroll 4).
//   LDS shrinks to reduce-only 49.5KB. Kills the 2-phase stall structure
//   (m233: stage+vmcnt+barrier ~72%) that R9-R11 counters showed.
// ---------------------------------------------------------------------------

typedef __bf16 bf16x8 __attribute__((ext_vector_type(8)));
typedef float  f32x4  __attribute__((ext_vector_type(4)));

#define N_NODE 4096
#define BATCH  128

// prep: [0,8192) adjB A-frag pack | [8192,9216) G0 B-frag pack = (X@W1)
//       | [9216,9243) zero hid
__global__ __launch_bounds__(256) void prep_k(const float* __restrict__ adj,
                                              __bf16* __restrict__ adjB,
                                              const float* __restrict__ X,
                                              const float* __restrict__ W1,
                                              __bf16* __restrict__ G0,
                                              float* __restrict__ hid_acc) {
    const int blk = blockIdx.x, tx = threadIdx.x;
    if (blk < 8192) {
        // A-frag pack: chunk g = (rb*128 + ka)*64 + lane holds
        // row = rb*16+(lane&15), k = ka*32+((lane>>4)&3)*8 .. +7
        const int g = blk * 256 + tx;
        const int lane = g & 63, ka = (g >> 6) & 127, rb = g >> 13;
        const int row = rb * 16 + (lane & 15);
        const int kb  = ka * 32 + ((lane >> 4) & 3) * 8;
        const float4* s = (const float4*)(adj + (size_t)row * 4096 + kb);
        float4 u = s[0];
        float4 v = s[1];
        bf16x8 o = { (__bf16)u.x, (__bf16)u.y, (__bf16)u.z, (__bf16)u.w,
                     (__bf16)v.x, (__bf16)v.y, (__bf16)v.z, (__bf16)v.w };
        *(bf16x8*)(adjB + (size_t)g * 8) = o;
    } else if (blk < 9216) {
        // B-frag pack: chunk g = (kc*32 + cb)*64 + lane holds
        // c = cb*16+(lane&15), m = kc*32+((lane>>4)&3)*8 .. +7
        const int g = (blk - 8192) * 256 + tx;
        const int lp = g & 63, cbg = (g >> 6) & 31, kc = g >> 11;
        const int c = cbg * 16 + (lp & 15);
        const int b = c >> 2, f = c & 3;
        const float w0 = W1[0 * 4 + f], w1 = W1[1 * 4 + f], w2 = W1[2 * 4 + f];
        const int mb = kc * 32 + ((lp >> 4) & 3) * 8;
        const float* Xb = X + (size_t)b * 12288 + (size_t)mb * 3;
        bf16x8 o;
#pragma unroll
        for (int j = 0; j < 8; ++j) {
            const float v = Xb[j * 3 + 0] * w0 + Xb[j * 3 + 1] * w1 + Xb[j * 3 + 2] * w2;
            o[j] = (__bf16)v;
        }
        *(bf16x8*)(G0 + (size_t)g * 8) = o;
    } else {
        const int i = (blk - 9216) * 256 + tx;
        if (i < BATCH * 54) hid_acc[i] = 0.f;
    }
}

// Fused GEMM + epilogue. Tile 64(M)x64(N), 4 waves: wk=wave owns k-slice
// [wk*32, wk*32+32) of each BK=128 macro-tile, computes the FULL 64x64 over
// it (4x4 frags). BOTH operands direct global->VGPR from frag-packed
// layouts; no LDS / barriers in the K-loop. Epilogue: linear tree-reduce
// over wk in LDS, wave0 transposes into Ct[64][66], all 256 threads write:
//   MODE 0: relu(C+b1) -> packed bf16       MODE 1: (relu(C@W2+b2))@W3 packed
//   MODE 2: relu(C+b3), f<3 -> H3 fp32 [b*3+f][n]
template <int MODE>
__global__ __launch_bounds__(256, 2) void gcn_k(const __bf16* __restrict__ A,
                                                const __bf16* __restrict__ Bp,
                                                const float* __restrict__ Wa,
                                                const float* __restrict__ ba,
                                                const float* __restrict__ Wb,
                                                __bf16* __restrict__ Op,
                                                float* __restrict__ H3out) {
    __shared__ __align__(16) unsigned char smem[50688];
    const int tx = threadIdx.x;
    const int wk = tx >> 6, lane = tx & 63;
    const int quad = lane >> 4, lr = lane & 15;

    const int l = blockIdx.x;
    const int xcd = l & 7, s = l >> 3;
    const int mi = xcd * 8 + (s & 7), ci = s >> 3;     // XCD: 8 mi panels
    const int m0 = mi * 64, c0 = ci * 64;

    // A frags: chunk (rb = mi*4+i, ka = kt*4+wk), elem off = chunk*8
    const __bf16* pA[4];
#pragma unroll
    for (int i = 0; i < 4; ++i)
        pA[i] = A + (size_t)(mi * 4 + i) * 65536 + wk * 512 + lane * 8;
    // B frags: chunk (kc = kt*4+wk, cb = ci*4+j)
    const __bf16* pB[4];
#pragma unroll
    for (int j = 0; j < 4; ++j)
        pB[j] = Bp + (size_t)(wk * 32 + ci * 4 + j) * 512 + lane * 8;

    f32x4 acc[4][4] = {};

#pragma unroll 4
    for (int kt = 0; kt < 32; ++kt) {
        bf16x8 af[4], bv[4];
#pragma unroll
        for (int i = 0; i < 4; ++i)
            af[i] = *(const bf16x8*)(pA[i] + kt * 2048);
#pragma unroll
        for (int j = 0; j < 4; ++j)
            bv[j] = *(const bf16x8*)(pB[j] + kt * 65536);
#pragma unroll
        for (int i = 0; i < 4; ++i)
#pragma unroll
            for (int j = 0; j < 4; ++j)
                acc[i][j] = __builtin_amdgcn_mfma_f32_16x16x32_bf16(
                    af[i], bv[j], acc[i][j], 0, 0, 0);
    }

    // ---- cross-wave k-reduce: linear t-major exchange (conflict-free) ----
    __syncthreads();
    float* part = (float*)smem;                        // 2 slots x 16KB
    const int sb = (wk >> 1) * 4096;
    if (wk & 1) {                                      // wk 1,3 write
#pragma unroll
        for (int t = 0; t < 16; ++t)
            *(f32x4*)(part + sb + t * 256 + lane * 4) = acc[t >> 2][t & 3];
    }
    __syncthreads();
    if (!(wk & 1)) {                                   // wk 0,2 add partner
#pragma unroll
        for (int t = 0; t < 16; ++t)
            acc[t >> 2][t & 3] += *(const f32x4*)(part + sb + t * 256 + lane * 4);
    }
    __syncthreads();
    if (wk == 2) {                                     // wk 2 writes its sum
#pragma unroll
        for (int t = 0; t < 16; ++t)
            *(f32x4*)(part + t * 256 + lane * 4) = acc[t >> 2][t & 3];
    }
    __syncthreads();
    float* Ct = (float*)(smem + 32768);                // [64][66]
    if (wk == 0) {                                     // full sum + transpose
#pragma unroll
        for (int t = 0; t < 16; ++t)
            acc[t >> 2][t & 3] += *(const f32x4*)(part + t * 256 + lane * 4);
        // C/D: col=lane&15, row=quad*4+reg (harness-verified)
#pragma unroll
        for (int i = 0; i < 4; ++i)
#pragma unroll
            for (int j = 0; j < 4; ++j)
#pragma unroll
                for (int r = 0; r < 4; ++r)
                    Ct[(i * 16 + quad * 4 + r) * 66 + j * 16 + lr] = acc[i][j][r];
    }
    __syncthreads();

    if (MODE == 0) {
#pragma unroll
        for (int it = 0; it < 2; ++it) {
            const int g = it * 256 + tx;           // 512 packed chunks/block
            const int lp = g & 63, cbl = (g >> 6) & 3, kcl = g >> 8;
            const int cl = cbl * 16 + (lp & 15);
            const float bf = ba[cl & 3];
            const int mb = kcl * 32 + ((lp >> 4) & 3) * 8;
            bf16x8 o;
#pragma unroll
            for (int j = 0; j < 8; ++j)
                o[j] = (__bf16)fmaxf(Ct[(mb + j) * 66 + cl] + bf, 0.f);
            *(bf16x8*)(Op + ((size_t)((mi * 2 + kcl) * 32 + (ci * 4 + cbl)) * 64 + lp) * 8) = o;
        }
    } else if (MODE == 1) {
        float W2l[16], W3l[12], bl2[4];
#pragma unroll
        for (int i = 0; i < 16; ++i) W2l[i] = Wa[i];
#pragma unroll
        for (int i = 0; i < 12; ++i) W3l[i] = Wb[i];
#pragma unroll
        for (int i = 0; i < 4; ++i) bl2[i] = ba[i];
#pragma unroll
        for (int it = 0; it < 2; ++it) {
            const int g = it * 256 + tx;
            const int lp = g & 63, cbl = (g >> 6) & 3, kcl = g >> 8;
            const int cl = cbl * 16 + (lp & 15);
            const int bloc = cl >> 2, f3 = cl & 3;
            const int mb = kcl * 32 + ((lp >> 4) & 3) * 8;
            bf16x8 o;
#pragma unroll
            for (int j = 0; j < 8; ++j) {
                const float* row = &Ct[(mb + j) * 66 + bloc * 4];
                float v = 0.f;
                if (f3 < 3) {
#pragma unroll
                    for (int fo = 0; fo < 4; ++fo) {
                        const float tmp = fmaxf(row[0] * W2l[fo] + row[1] * W2l[4 + fo] +
                                                row[2] * W2l[8 + fo] + row[3] * W2l[12 + fo] +
                                                bl2[fo], 0.f);
                        const float w3a = W3l[fo * 3 + 0], w3b = W3l[fo * 3 + 1],
                                    w3c = W3l[fo * 3 + 2];
                        v += tmp * (f3 == 0 ? w3a : (f3 == 1 ? w3b : w3c));
                    }
                }
                o[j] = (__bf16)v;                  // f3==3 -> 0 pad column
            }
            *(bf16x8*)(Op + ((size_t)((mi * 2 + kcl) * 32 + (ci * 4 + cbl)) * 64 + lp) * 8) = o;
        }
    } else {
        const int m_l = tx & 63, cq = tx >> 6;
#pragma unroll
        for (int t = 0; t < 16; ++t) {
            const int cl = cq * 16 + t;
            const int c = c0 + cl, b = c >> 2, f = c & 3;
            if (f < 3)
                H3out[(size_t)(b * 3 + f) * N_NODE + m0 + m_l] =
                    fmaxf(Ct[m_l * 66 + cl] + ba[f], 0.f);
        }
    }
}

// fc1 split-K partial sums: grid (64 n-chunks, 8 b-groups of 16).
__global__ __launch_bounds__(256) void fc1p_k(const float* __restrict__ H3,
                                              const float* __restrict__ Wfc,
                                              float* __restrict__ hid_acc) {
    __shared__ float hs[16 * 192];       // [b][f][n]
    __shared__ float red[4][16][64];
    const int tx = threadIdx.x;
    const int wv = tx >> 6, lane = tx & 63;
    const int n0 = blockIdx.x * 64;
    const int b0 = blockIdx.y * 16;

    for (int idx = tx; idx < 3072; idx += 256) {
        const int n = idx & 63, f = (idx >> 6) % 3, b = idx / 192;
        hs[idx] = H3[((size_t)((b0 + b) * 3 + f)) * N_NODE + n0 + n];
    }
    __syncthreads();

    float acc[16];
#pragma unroll
    for (int b = 0; b < 16; ++b) acc[b] = 0.f;
    if (lane < 54) {
        const int nb = wv * 16;
        for (int n = 0; n < 16; ++n) {
#pragma unroll
            for (int f = 0; f < 3; ++f) {
                const float w = Wfc[((size_t)(n0 + nb + n) * 3 + f) * 54 + lane];
#pragma unroll
                for (int b = 0; b < 16; ++b)
                    acc[b] += hs[b * 192 + f * 64 + nb + n] * w;
            }
        }
    }
#pragma unroll
    for (int b = 0; b < 16; ++b) red[wv][b][lane] = acc[b];
    __syncthreads();
    if (wv == 0 && lane < 54) {
        for (int b = 0; b < 16; ++b) {
            const float s = red[0][b][lane] + red[1][b][lane] +
                            red[2][b][lane] + red[3][b][lane];
            atomicAdd(&hid_acc[(b0 + b) * 54 + lane], s);
        }
    }
}

// out[b][a] = sum_j relu(hid_acc[b][j]+bfc[j]) * Wout[j][a] + bout[a]
__global__ __launch_bounds__(256) void fc2_k(const float* __restrict__ hid_acc,
                                             const float* __restrict__ bfc,
                                             const float* __restrict__ Wout,
                                             const float* __restrict__ bout,
                                             float* __restrict__ out) {
    const int tx = threadIdx.x;
    const int a  = blockIdx.x * 256 + tx;
    const int b0 = blockIdx.y * 4;
    __shared__ float hs[4 * 54];
    if (tx < 216) {
        const int j = tx % 54;
        hs[tx] = fmaxf(hid_acc[b0 * 54 + tx] + bfc[j], 0.f);
    }
    __syncthreads();
    float a0 = 0.f, a1 = 0.f, a2 = 0.f, a3 = 0.f;
    for (int j = 0; j < 54; ++j) {
        float w = Wout[(size_t)j * N_NODE + a];
        a0 += hs[0 * 54 + j] * w;
        a1 += hs[1 * 54 + j] * w;
        a2 += hs[2 * 54 + j] * w;
        a3 += hs[3 * 54 + j] * w;
    }
    float bo = bout[a];
    out[(size_t)(b0 + 0) * N_NODE + a] = a0 + bo;
    out[(size_t)(b0 + 1) * N_NODE + a] = a1 + bo;
    out[(size_t)(b0 + 2) * N_NODE + a] = a2 + bo;
    out[(size_t)(b0 + 3) * N_NODE + a] = a3 + bo;
}

extern "C" void kernel_launch(void* const* d_in, const int* in_sizes, int n_in,
                              void* d_out, int out_size, void* d_ws, size_t ws_size,
                              hipStream_t stream) {
    const float* X    = (const float*)d_in[0];
    const float* adj  = (const float*)d_in[1];
    const float* W1   = (const float*)d_in[2];
    const float* b1   = (const float*)d_in[3];
    const float* W2   = (const float*)d_in[4];
    const float* b2   = (const float*)d_in[5];
    const float* W3   = (const float*)d_in[6];
    const float* b3   = (const float*)d_in[7];
    const float* Wfc  = (const float*)d_in[8];
    const float* bfc  = (const float*)d_in[9];
    const float* Wout = (const float*)d_in[10];
    const float* bout = (const float*)d_in[11];
    float* out = (float*)d_out;

    // ws: adjB (A-pack) 32MB | G0 packed 4MB | H1 packed 4MB | H2g packed 4MB
    //   | H3 fp32 [384][4096] 6MB | hid [128][54]
    char* w = (char*)d_ws;
    __bf16* adjB = (__bf16*)w;
    __bf16* G0   = (__bf16*)(w + 33554432);
    __bf16* H1   = (__bf16*)(w + 33554432 + 4194304);
    __bf16* H2g  = (__bf16*)(w + 33554432 + 2 * 4194304);
    float*  H3   = (float*)(w + 33554432 + 3 * 4194304);
    float*  hid  = (float*)(w + 33554432 + 3 * 4194304 + 6291456);

    prep_k<<<9243, 256, 0, stream>>>(adj, adjB, X, W1, G0, hid);

    // stage 1: H1 = relu(adj @ G0 + b1)            (W1 pre-applied in prep)
    gcn_k<0><<<512, 256, 0, stream>>>(adjB, G0, nullptr, b1, nullptr, H1, nullptr);
    // stage 2: H2g = (relu(adj @ H1 @ W2 + b2)) @ W3, padded f=4
    gcn_k<1><<<512, 256, 0, stream>>>(adjB, H1, W2, b2, W3, H2g, nullptr);
    // stage 3: H3 = relu(adj @ H2g + b3), f<3, fp32
    gcn_k<2><<<512, 256, 0, stream>>>(adjB, H2g, nullptr, b3, nullptr, nullptr, H3);

    // FC head
    fc1p_k<<<dim3(64, 8), 256, 0, stream>>>(H3, Wfc, hid);
    fc2_k<<<dim3(16, 32), 256, 0, stream>>>(hid, bfc, Wout, bout, out);
}

// Round 6
// 218.440 us; speedup vs baseline: 1.0450x; 1.0450x over previous
//
#include <hip/hip_runtime.h>

// ---------------------------------------------------------------------------
// sxsGCN: h=[B=128,N=4096,3]; 3x { relu((adj@h)@W+b) }; then FC 12288->54->4096
// bf16 MFMA GEMMs adj[4096x4096] @ H[4096 x 512].
// R9..R11: packed-B, counted-vmcnt, 2 blk/CU: GEMMs stuck 34-41us, pipes idle.
// R12: cooperative mega-kernel FAIL: harness 0xAA fill leaves stale lines in
//   reader XCDs' L2; grid.sync doesn't invalidate per-XCD L2 (kernel
//   boundaries do). Device-sync fusion is off the table.
// R13: barrier-free GEMM (both operands frag-packed, global->VGPR, no LDS in
//   K-loop): 228us. GEMM pinned ~35us by VMEM service; audit shows ~55us of
//   dispatch gaps/tails across the 6-kernel chain.
// R14: algebraic fusion instead of device sync:
//   - fc1 fused into gcn<2> epilogue: block (mi,ci) owns nodes m0..m0+63 x
//     batches ci*16..+15 -> computes its full hid contribution (lane=j, 16
//     batch-accs in regs, 1 coalesced Wfc load per 16 FMAs) + atomicAdd
//     (device-scope, cross-XCD safe). Deletes H3 (12MB traffic), fc1p kernel,
//     one launch gap.
//   - parallel epilogue reduce: all 4 waves write slots, wave wk reduces +
//     transposes i-quarter wk. 3 syncs (was 5), no wave0-serial section.
// ---------------------------------------------------------------------------

typedef __bf16 bf16x8 __attribute__((ext_vector_type(8)));
typedef float  f32x4  __attribute__((ext_vector_type(4)));

#define N_NODE 4096
#define BATCH  128

// prep: [0,8192) adjB A-frag pack | [8192,9216) G0 B-frag pack = (X@W1)
//       | [9216,9243) zero hid
__global__ __launch_bounds__(256) void prep_k(const float* __restrict__ adj,
                                              __bf16* __restrict__ adjB,
                                              const float* __restrict__ X,
                                              const float* __restrict__ W1,
                                              __bf16* __restrict__ G0,
                                              float* __restrict__ hid_acc) {
    const int blk = blockIdx.x, tx = threadIdx.x;
    if (blk < 8192) {
        // A-frag pack: chunk g = (rb*128 + ka)*64 + lane holds
        // row = rb*16+(lane&15), k = ka*32+((lane>>4)&3)*8 .. +7
        const int g = blk * 256 + tx;
        const int lane = g & 63, ka = (g >> 6) & 127, rb = g >> 13;
        const int row = rb * 16 + (lane & 15);
        const int kb  = ka * 32 + ((lane >> 4) & 3) * 8;
        const float4* s = (const float4*)(adj + (size_t)row * 4096 + kb);
        float4 u = s[0];
        float4 v = s[1];
        bf16x8 o = { (__bf16)u.x, (__bf16)u.y, (__bf16)u.z, (__bf16)u.w,
                     (__bf16)v.x, (__bf16)v.y, (__bf16)v.z, (__bf16)v.w };
        *(bf16x8*)(adjB + (size_t)g * 8) = o;
    } else if (blk < 9216) {
        // B-frag pack: chunk g = (kc*32 + cb)*64 + lane holds
        // c = cb*16+(lane&15), m = kc*32+((lane>>4)&3)*8 .. +7
        const int g = (blk - 8192) * 256 + tx;
        const int lp = g & 63, cbg = (g >> 6) & 31, kc = g >> 11;
        const int c = cbg * 16 + (lp & 15);
        const int b = c >> 2, f = c & 3;
        const float w0 = W1[0 * 4 + f], w1 = W1[1 * 4 + f], w2 = W1[2 * 4 + f];
        const int mb = kc * 32 + ((lp >> 4) & 3) * 8;
        const float* Xb = X + (size_t)b * 12288 + (size_t)mb * 3;
        bf16x8 o;
#pragma unroll
        for (int j = 0; j < 8; ++j) {
            const float v = Xb[j * 3 + 0] * w0 + Xb[j * 3 + 1] * w1 + Xb[j * 3 + 2] * w2;
            o[j] = (__bf16)v;
        }
        *(bf16x8*)(G0 + (size_t)g * 8) = o;
    } else {
        const int i = (blk - 9216) * 256 + tx;
        if (i < BATCH * 54) hid_acc[i] = 0.f;
    }
}

// Fused GEMM + epilogue. Tile 64(M)x64(N), 4 waves: wk=wave owns k-slice
// [wk*32, wk*32+32) of each BK=128 macro-tile, computes the FULL 64x64 over
// it (4x4 frags). BOTH operands direct global->VGPR from frag-packed
// layouts; no LDS / barriers in the K-loop. Epilogue: parallel slot-reduce
// (wave wk reduces + transposes i-quarter wk into Ct[64][66] @ smem base).
//   MODE 0: relu(C+b1) -> packed bf16       MODE 1: (relu(C@W2+b2))@W3 packed
//   MODE 2: fused fc1: hid[b][j] += sum_{n,f} relu(C+b3) * Wfc  (atomicAdd)
template <int MODE>
__global__ __launch_bounds__(256, 2) void gcn_k(const __bf16* __restrict__ A,
                                                const __bf16* __restrict__ Bp,
                                                const float* __restrict__ Wa,
                                                const float* __restrict__ ba,
                                                const float* __restrict__ Wb,
                                                __bf16* __restrict__ Op,
                                                float* __restrict__ hidOut) {
    __shared__ __align__(16) unsigned char smem[65536];
    const int tx = threadIdx.x;
    const int wk = tx >> 6, lane = tx & 63;
    const int quad = lane >> 4, lr = lane & 15;

    const int l = blockIdx.x;
    const int xcd = l & 7, s = l >> 3;
    const int mi = xcd * 8 + (s & 7), ci = s >> 3;     // XCD: 8 mi panels
    const int m0 = mi * 64;

    // A frags: chunk (rb = mi*4+i, ka = kt*4+wk), elem off = chunk*8
    const __bf16* pA[4];
#pragma unroll
    for (int i = 0; i < 4; ++i)
        pA[i] = A + (size_t)(mi * 4 + i) * 65536 + wk * 512 + lane * 8;
    // B frags: chunk (kc = kt*4+wk, cb = ci*4+j)
    const __bf16* pB[4];
#pragma unroll
    for (int j = 0; j < 4; ++j)
        pB[j] = Bp + (size_t)(wk * 32 + ci * 4 + j) * 512 + lane * 8;

    f32x4 acc[4][4] = {};

#pragma unroll 4
    for (int kt = 0; kt < 32; ++kt) {
        bf16x8 af[4], bv[4];
#pragma unroll
        for (int i = 0; i < 4; ++i)
            af[i] = *(const bf16x8*)(pA[i] + kt * 2048);
#pragma unroll
        for (int j = 0; j < 4; ++j)
            bv[j] = *(const bf16x8*)(pB[j] + kt * 65536);
#pragma unroll
        for (int i = 0; i < 4; ++i)
#pragma unroll
            for (int j = 0; j < 4; ++j)
                acc[i][j] = __builtin_amdgcn_mfma_f32_16x16x32_bf16(
                    af[i], bv[j], acc[i][j], 0, 0, 0);
    }

    // ---- parallel cross-wave k-reduce: 4 slots x 16KB, linear layout ----
    float* part = (float*)smem;
#pragma unroll
    for (int t = 0; t < 16; ++t)
        *(f32x4*)(part + wk * 4096 + t * 256 + lane * 4) = acc[t >> 2][t & 3];
    __syncthreads();
    f32x4 fin[4];                        // wave wk owns t = wk*4+u (i=wk, j=u)
#pragma unroll
    for (int u = 0; u < 4; ++u) {
        const int t = wk * 4 + u;
        f32x4 s0 = *(const f32x4*)(part + 0     + t * 256 + lane * 4);
        f32x4 s1 = *(const f32x4*)(part + 4096  + t * 256 + lane * 4);
        f32x4 s2 = *(const f32x4*)(part + 8192  + t * 256 + lane * 4);
        f32x4 s3 = *(const f32x4*)(part + 12288 + t * 256 + lane * 4);
        fin[u] = (s0 + s1) + (s2 + s3);
    }
    __syncthreads();                     // all slot reads done; reuse as Ct
    float* Ct = (float*)smem;            // [64][66] floats (16.9KB)
    // C/D: col=lane&15, row=quad*4+reg (harness-verified); rows i=wk quarter
#pragma unroll
    for (int u = 0; u < 4; ++u)
#pragma unroll
        for (int r = 0; r < 4; ++r)
            Ct[(wk * 16 + quad * 4 + r) * 66 + u * 16 + lr] = fin[u][r];
    __syncthreads();

    if (MODE == 0) {
#pragma unroll
        for (int it = 0; it < 2; ++it) {
            const int g = it * 256 + tx;           // 512 packed chunks/block
            const int lp = g & 63, cbl = (g >> 6) & 3, kcl = g >> 8;
            const int cl = cbl * 16 + (lp & 15);
            const float bf = ba[cl & 3];
            const int mb = kcl * 32 + ((lp >> 4) & 3) * 8;
            bf16x8 o;
#pragma unroll
            for (int j = 0; j < 8; ++j)
                o[j] = (__bf16)fmaxf(Ct[(mb + j) * 66 + cl] + bf, 0.f);
            *(bf16x8*)(Op + ((size_t)((mi * 2 + kcl) * 32 + (ci * 4 + cbl)) * 64 + lp) * 8) = o;
        }
    } else if (MODE == 1) {
        float W2l[16], W3l[12], bl2[4];
#pragma unroll
        for (int i = 0; i < 16; ++i) W2l[i] = Wa[i];
#pragma unroll
        for (int i = 0; i < 12; ++i) W3l[i] = Wb[i];
#pragma unroll
        for (int i = 0; i < 4; ++i) bl2[i] = ba[i];
#pragma unroll
        for (int it = 0; it < 2; ++it) {
            const int g = it * 256 + tx;
            const int lp = g & 63, cbl = (g >> 6) & 3, kcl = g >> 8;
            const int cl = cbl * 16 + (lp & 15);
            const int bloc = cl >> 2, f3 = cl & 3;
            const int mb = kcl * 32 + ((lp >> 4) & 3) * 8;
            bf16x8 o;
#pragma unroll
            for (int j = 0; j < 8; ++j) {
                const float* row = &Ct[(mb + j) * 66 + bloc * 4];
                float v = 0.f;
                if (f3 < 3) {
#pragma unroll
                    for (int fo = 0; fo < 4; ++fo) {
                        const float tmp = fmaxf(row[0] * W2l[fo] + row[1] * W2l[4 + fo] +
                                                row[2] * W2l[8 + fo] + row[3] * W2l[12 + fo] +
                                                bl2[fo], 0.f);
                        const float w3a = W3l[fo * 3 + 0], w3b = W3l[fo * 3 + 1],
                                    w3c = W3l[fo * 3 + 2];
                        v += tmp * (f3 == 0 ? w3a : (f3 == 1 ? w3b : w3c));
                    }
                }
                o[j] = (__bf16)v;                  // f3==3 -> 0 pad column
            }
            *(bf16x8*)(Op + ((size_t)((mi * 2 + kcl) * 32 + (ci * 4 + cbl)) * 64 + lp) * 8) = o;
        }
    } else {
        // ---- fused fc1: this block owns nodes m0..m0+63, batches ci*16..+15.
        // lane = j (0..53); wave wk handles nodes wk*16..+15; 16 batch-accs
        // in regs; 1 coalesced Wfc load per (n,f) feeds 16 FMAs (Ct reads are
        // same-address broadcasts). Cross-wave reduce in LDS, wave0 atomics.
        float* red = (float*)(smem + 17408);       // [4][16][64] floats, 16KB
        const float b30 = ba[0], b31 = ba[1], b32 = ba[2];
        float accf[16];
#pragma unroll
        for (int b = 0; b < 16; ++b) accf[b] = 0.f;
        if (lane < 54) {
            for (int nn = 0; nn < 16; ++nn) {
                const int n = wk * 16 + nn;
#pragma unroll
                for (int f = 0; f < 3; ++f) {
                    const float w = Wa[((size_t)(m0 + n) * 3 + f) * 54 + lane];
                    const float bf = (f == 0) ? b30 : (f == 1 ? b31 : b32);
#pragma unroll
                    for (int b = 0; b < 16; ++b) {
                        const float r = fmaxf(Ct[n * 66 + b * 4 + f] + bf, 0.f);
                        accf[b] += r * w;
                    }
                }
            }
        }
#pragma unroll
        for (int b = 0; b < 16; ++b) red[(wk * 16 + b) * 64 + lane] = accf[b];
        __syncthreads();
        if (wk == 0 && lane < 54) {
            for (int b = 0; b < 16; ++b) {
                const float s2 = red[b * 64 + lane] + red[(16 + b) * 64 + lane] +
                                 red[(32 + b) * 64 + lane] + red[(48 + b) * 64 + lane];
                atomicAdd(&hidOut[(ci * 16 + b) * 54 + lane], s2);
            }
        }
    }
}

// out[b][a] = sum_j relu(hid_acc[b][j]+bfc[j]) * Wout[j][a] + bout[a]
__global__ __launch_bounds__(256) void fc2_k(const float* __restrict__ hid_acc,
                                             const float* __restrict__ bfc,
                                             const float* __restrict__ Wout,
                                             const float* __restrict__ bout,
                                             float* __restrict__ out) {
    const int tx = threadIdx.x;
    const int a  = blockIdx.x * 256 + tx;
    const int b0 = blockIdx.y * 4;
    __shared__ float hs[4 * 54];
    if (tx < 216) {
        const int j = tx % 54;
        hs[tx] = fmaxf(hid_acc[b0 * 54 + tx] + bfc[j], 0.f);
    }
    __syncthreads();
    float a0 = 0.f, a1 = 0.f, a2 = 0.f, a3 = 0.f;
    for (int j = 0; j < 54; ++j) {
        float w = Wout[(size_t)j * N_NODE + a];
        a0 += hs[0 * 54 + j] * w;
        a1 += hs[1 * 54 + j] * w;
        a2 += hs[2 * 54 + j] * w;
        a3 += hs[3 * 54 + j] * w;
    }
    float bo = bout[a];
    out[(size_t)(b0 + 0) * N_NODE + a] = a0 + bo;
    out[(size_t)(b0 + 1) * N_NODE + a] = a1 + bo;
    out[(size_t)(b0 + 2) * N_NODE + a] = a2 + bo;
    out[(size_t)(b0 + 3) * N_NODE + a] = a3 + bo;
}

extern "C" void kernel_launch(void* const* d_in, const int* in_sizes, int n_in,
                              void* d_out, int out_size, void* d_ws, size_t ws_size,
                              hipStream_t stream) {
    const float* X    = (const float*)d_in[0];
    const float* adj  = (const float*)d_in[1];
    const float* W1   = (const float*)d_in[2];
    const float* b1   = (const float*)d_in[3];
    const float* W2   = (const float*)d_in[4];
    const float* b2   = (const float*)d_in[5];
    const float* W3   = (const float*)d_in[6];
    const float* b3   = (const float*)d_in[7];
    const float* Wfc  = (const float*)d_in[8];
    const float* bfc  = (const float*)d_in[9];
    const float* Wout = (const float*)d_in[10];
    const float* bout = (const float*)d_in[11];
    float* out = (float*)d_out;

    // ws: adjB (A-pack) 32MB | G0 packed 4MB | H1 packed 4MB | H2g packed 4MB
    //   | hid [128][54]
    char* w = (char*)d_ws;
    __bf16* adjB = (__bf16*)w;
    __bf16* G0   = (__bf16*)(w + 33554432);
    __bf16* H1   = (__bf16*)(w + 33554432 + 4194304);
    __bf16* H2g  = (__bf16*)(w + 33554432 + 2 * 4194304);
    float*  hid  = (float*)(w + 33554432 + 3 * 4194304);

    prep_k<<<9243, 256, 0, stream>>>(adj, adjB, X, W1, G0, hid);

    // stage 1: H1 = relu(adj @ G0 + b1)            (W1 pre-applied in prep)
    gcn_k<0><<<512, 256, 0, stream>>>(adjB, G0, nullptr, b1, nullptr, H1, nullptr);
    // stage 2: H2g = (relu(adj @ H1 @ W2 + b2)) @ W3, padded f=4
    gcn_k<1><<<512, 256, 0, stream>>>(adjB, H1, W2, b2, W3, H2g, nullptr);
    // stage 3: fused  relu(adj @ H2g + b3)  +  fc1 partial sums -> hid
    gcn_k<2><<<512, 256, 0, stream>>>(adjB, H2g, Wfc, b3, nullptr, nullptr, hid);

    // FC head tail
    fc2_k<<<dim3(16, 32), 256, 0, stream>>>(hid, bfc, Wout, bout, out);
}

// Round 9
// 209.239 us; speedup vs baseline: 1.0909x; 1.0440x over previous
//
#include <hip/hip_runtime.h>

// ---------------------------------------------------------------------------
// sxsGCN: h=[B=128,N=4096,3]; 3x { relu((adj@h)@W+b) }; then FC 12288->54->4096
// bf16 MFMA GEMMs adj[4096x4096] @ H[4096 x 512].
// R13: barrier-free GEMM, both operands frag-packed global->VGPR: ~35us/gemm.
// R14: fc1 fused into gcn<2>, H3/fc1p deleted: 218us PASS. Counters: all
//   pipes idle (Mfma 15, VALU 22, HBM 11, Occ 18.6) at 2 waves/SIMD.
// R15: CRASH: 66,048B static __shared__ > 64KB static limit -> launch abort.
// R16: 8-way k-slice 512-thr blocks; FAIL: reduce-slot stride bug --
//   (wave*4+u)*1024 floats addressed 128KB of LDS against a 49.7KB buffer
//   (slot = 256 floats, not 1024) -> OOB writes corrupted accumulators.
//   Structure never actually tested.
// R17: R16 with the stride fixed (1024 -> 256 in slot write + reduce read).
//   SAME 512 tiles of 64x64; 512 threads = 8 k-slice waves; acc[4][4]/wave;
//   16 steps of BK=256. 4096 waves = 16/CU = 4 waves/SIMD (2 blk/CU:
//   VGPR<=128 via lb(512,4), LDS 49,664B). Reduce: 4 static rounds, 32KB
//   slots -> Ct[64][66]. Epilogue formulas = R14 (proven), 8-wave split.
// ---------------------------------------------------------------------------

typedef __bf16 bf16x8 __attribute__((ext_vector_type(8)));
typedef float  f32x4  __attribute__((ext_vector_type(4)));

#define N_NODE 4096
#define BATCH  128

// prep: [0,8192) adjB A-frag pack | [8192,9216) G0 B-frag pack = (X@W1)
//       | [9216,9243) zero hid
__global__ __launch_bounds__(256) void prep_k(const float* __restrict__ adj,
                                              __bf16* __restrict__ adjB,
                                              const float* __restrict__ X,
                                              const float* __restrict__ W1,
                                              __bf16* __restrict__ G0,
                                              float* __restrict__ hid_acc) {
    const int blk = blockIdx.x, tx = threadIdx.x;
    if (blk < 8192) {
        // A-frag pack: chunk g = (rb*128 + ka)*64 + lane holds
        // row = rb*16+(lane&15), k = ka*32+((lane>>4)&3)*8 .. +7
        const int g = blk * 256 + tx;
        const int lane = g & 63, ka = (g >> 6) & 127, rb = g >> 13;
        const int row = rb * 16 + (lane & 15);
        const int kb  = ka * 32 + ((lane >> 4) & 3) * 8;
        const float4* s = (const float4*)(adj + (size_t)row * 4096 + kb);
        float4 u = s[0];
        float4 v = s[1];
        bf16x8 o = { (__bf16)u.x, (__bf16)u.y, (__bf16)u.z, (__bf16)u.w,
                     (__bf16)v.x, (__bf16)v.y, (__bf16)v.z, (__bf16)v.w };
        *(bf16x8*)(adjB + (size_t)g * 8) = o;
    } else if (blk < 9216) {
        // B-frag pack: chunk g = (kc*32 + cb)*64 + lane holds
        // c = cb*16+(lane&15), m = kc*32+((lane>>4)&3)*8 .. +7
        const int g = (blk - 8192) * 256 + tx;
        const int lp = g & 63, cbg = (g >> 6) & 31, kc = g >> 11;
        const int c = cbg * 16 + (lp & 15);
        const int b = c >> 2, f = c & 3;
        const float w0 = W1[0 * 4 + f], w1 = W1[1 * 4 + f], w2 = W1[2 * 4 + f];
        const int mb = kc * 32 + ((lp >> 4) & 3) * 8;
        const float* Xb = X + (size_t)b * 12288 + (size_t)mb * 3;
        bf16x8 o;
#pragma unroll
        for (int j = 0; j < 8; ++j) {
            const float v = Xb[j * 3 + 0] * w0 + Xb[j * 3 + 1] * w1 + Xb[j * 3 + 2] * w2;
            o[j] = (__bf16)v;
        }
        *(bf16x8*)(G0 + (size_t)g * 8) = o;
    } else {
        const int i = (blk - 9216) * 256 + tx;
        if (i < BATCH * 54) hid_acc[i] = 0.f;
    }
}

// Fused GEMM + epilogue. Tile 64(M)x64(N), 512 threads = 8 waves; wave owns
// k-chunks ka = kt*8+wave (16 steps of BK=256), acc[4][4].
// Both operands direct global->VGPR, frag-packed; no LDS/barriers in K-loop.
// Epilogue: 4 static rounds of 8-slot exchange -> Ct[64][66]; then:
//   MODE 0: relu(C+b1) -> packed bf16       MODE 1: (relu(C@W2+b2))@W3 packed
//   MODE 2: fused fc1: hid[b][j] += sum_{n,f} relu(C+b3)*Wfc (atomicAdd)
template <int MODE>
__global__ __launch_bounds__(512, 4) void gcn_k(const __bf16* __restrict__ A,
                                                const __bf16* __restrict__ Bp,
                                                const float* __restrict__ Wa,
                                                const float* __restrict__ ba,
                                                const float* __restrict__ Wb,
                                                __bf16* __restrict__ Op,
                                                float* __restrict__ hidOut) {
    __shared__ __align__(16) unsigned char smem[49664];
    const int tx = threadIdx.x;
    const int wave = tx >> 6, lane = tx & 63;
    const int quad = lane >> 4, lr = lane & 15;

    const int l = blockIdx.x;
    const int xcd = l & 7, s = l >> 3;
    const int mi = xcd * 8 + (s & 7), ci = s >> 3;     // mi 0..63, ci 0..7
    const int m0 = mi * 64;

    // A frags: chunk (rb = mi*4+i, ka = kt*8+wave)
    const __bf16* pA[4];
#pragma unroll
    for (int i = 0; i < 4; ++i)
        pA[i] = A + (size_t)(mi * 4 + i) * 65536 + wave * 512 + lane * 8;
    // B frags: chunk (kc = kt*8+wave, cb = ci*4+j)
    const __bf16* pB[4];
#pragma unroll
    for (int j = 0; j < 4; ++j)
        pB[j] = Bp + (size_t)(wave * 32 + (ci * 4 + j)) * 512 + lane * 8;

    f32x4 acc[4][4] = {};

#pragma unroll 4
    for (int kt = 0; kt < 16; ++kt) {
        bf16x8 af[4], bv[4];
#pragma unroll
        for (int i = 0; i < 4; ++i)
            af[i] = *(const bf16x8*)(pA[i] + kt * 4096);
#pragma unroll
        for (int j = 0; j < 4; ++j)
            bv[j] = *(const bf16x8*)(pB[j] + kt * 131072);
#pragma unroll
        for (int i = 0; i < 4; ++i)
#pragma unroll
            for (int j = 0; j < 4; ++j)
                acc[i][j] = __builtin_amdgcn_mfma_f32_16x16x32_bf16(
                    af[i], bv[j], acc[i][j], 0, 0, 0);
    }

    // ---- 8-way cross-wave k-reduce: 4 static rounds ----
    // slots: [8 waves][4 u] x (64 lanes x f32x4 = 256 floats = 1KB) = 32KB;
    // Ct[64][66] f32 at +32768 (16,896B). Total = 49,664B.
    float* part = (float*)smem;
    float* Ct   = (float*)(smem + 32768);
#pragma unroll
    for (int r = 0; r < 4; ++r) {
        __syncthreads();                 // slots free (prev round consumed)
#pragma unroll
        for (int u = 0; u < 4; ++u)
            *(f32x4*)(part + (wave * 4 + u) * 256 + lane * 4) = acc[r][u];
        __syncthreads();
        if (wave < 4) {                  // wave w reduces u=w across 8 slots
            f32x4 fin = {};
#pragma unroll
            for (int sl = 0; sl < 8; ++sl)
                fin += *(const f32x4*)(part + (sl * 4 + wave) * 256 + lane * 4);
            // C/D: col=lane&15, row=quad*4+reg (harness-verified)
#pragma unroll
            for (int rr = 0; rr < 4; ++rr)
                Ct[(r * 16 + quad * 4 + rr) * 66 + wave * 16 + lr] = fin[rr];
        }
    }
    __syncthreads();                     // Ct complete

    if (MODE == 0) {
        const int g2 = tx;               // 512 packed chunks/block, one pass
        const int lp = g2 & 63, cbl = (g2 >> 6) & 3, kcl = g2 >> 8;
        const int cl = cbl * 16 + (lp & 15);
        const float bf = ba[cl & 3];
        const int mb = kcl * 32 + ((lp >> 4) & 3) * 8;
        bf16x8 o;
#pragma unroll
        for (int j = 0; j < 8; ++j)
            o[j] = (__bf16)fmaxf(Ct[(mb + j) * 66 + cl] + bf, 0.f);
        *(bf16x8*)(Op + ((size_t)((mi * 2 + kcl) * 32 + (ci * 4 + cbl)) * 64 + lp) * 8) = o;
    } else if (MODE == 1) {
        float W2l[16], W3l[12], bl2[4];
#pragma unroll
        for (int i = 0; i < 16; ++i) W2l[i] = Wa[i];
#pragma unroll
        for (int i = 0; i < 12; ++i) W3l[i] = Wb[i];
#pragma unroll
        for (int i = 0; i < 4; ++i) bl2[i] = ba[i];
        const int g2 = tx;
        const int lp = g2 & 63, cbl = (g2 >> 6) & 3, kcl = g2 >> 8;
        const int cl = cbl * 16 + (lp & 15);
        const int bloc = cl >> 2, f3 = cl & 3;
        const int mb = kcl * 32 + ((lp >> 4) & 3) * 8;
        bf16x8 o;
#pragma unroll
        for (int j = 0; j < 8; ++j) {
            const float* row = &Ct[(mb + j) * 66 + bloc * 4];
            float v = 0.f;
            if (f3 < 3) {
#pragma unroll
                for (int fo = 0; fo < 4; ++fo) {
                    const float tmp = fmaxf(row[0] * W2l[fo] + row[1] * W2l[4 + fo] +
                                            row[2] * W2l[8 + fo] + row[3] * W2l[12 + fo] +
                                            bl2[fo], 0.f);
                    const float w3a = W3l[fo * 3 + 0], w3b = W3l[fo * 3 + 1],
                                w3c = W3l[fo * 3 + 2];
                    v += tmp * (f3 == 0 ? w3a : (f3 == 1 ? w3b : w3c));
                }
            }
            o[j] = (__bf16)v;            // f3==3 -> 0 pad column
        }
        *(bf16x8*)(Op + ((size_t)((mi * 2 + kcl) * 32 + (ci * 4 + cbl)) * 64 + lp) * 8) = o;
    } else {
        // ---- fused fc1: block owns nodes m0..m0+63, batches ci*16..+15.
        // wave handles nodes wave*8..+7; lane=j (0..53); 16 batch-accs.
        // red [8][16][64] f32 = 32KB reuses the slot region (rounds done).
        float* red = part;
        const float b30 = ba[0], b31 = ba[1], b32 = ba[2];
        float accf[16];
#pragma unroll
        for (int b = 0; b < 16; ++b) accf[b] = 0.f;
        if (lane < 54) {
            for (int nn = 0; nn < 8; ++nn) {
                const int n = wave * 8 + nn;
#pragma unroll
                for (int f = 0; f < 3; ++f) {
                    const float w = Wa[((size_t)(m0 + n) * 3 + f) * 54 + lane];
                    const float bf = (f == 0) ? b30 : (f == 1 ? b31 : b32);
#pragma unroll
                    for (int b = 0; b < 16; ++b) {
                        const float r = fmaxf(Ct[n * 66 + b * 4 + f] + bf, 0.f);
                        accf[b] += r * w;
                    }
                }
            }
        }
#pragma unroll
        for (int b = 0; b < 16; ++b)
            red[(wave * 16 + b) * 64 + lane] = accf[b];
        __syncthreads();
        if (wave == 0 && lane < 54) {
            for (int b = 0; b < 16; ++b) {
                float s2 = 0.f;
#pragma unroll
                for (int w8 = 0; w8 < 8; ++w8)
                    s2 += red[(w8 * 16 + b) * 64 + lane];
                atomicAdd(&hidOut[(ci * 16 + b) * 54 + lane], s2);
            }
        }
    }
}

// out[b][a] = sum_j relu(hid_acc[b][j]+bfc[j]) * Wout[j][a] + bout[a]
__global__ __launch_bounds__(256) void fc2_k(const float* __restrict__ hid_acc,
                                             const float* __restrict__ bfc,
                                             const float* __restrict__ Wout,
                                             const float* __restrict__ bout,
                                             float* __restrict__ out) {
    const int tx = threadIdx.x;
    const int a  = blockIdx.x * 256 + tx;
    const int b0 = blockIdx.y * 4;
    __shared__ float hs[4 * 54];
    if (tx < 216) {
        const int j = tx % 54;
        hs[tx] = fmaxf(hid_acc[b0 * 54 + tx] + bfc[j], 0.f);
    }
    __syncthreads();
    float a0 = 0.f, a1 = 0.f, a2 = 0.f, a3 = 0.f;
    for (int j = 0; j < 54; ++j) {
        float w = Wout[(size_t)j * N_NODE + a];
        a0 += hs[0 * 54 + j] * w;
        a1 += hs[1 * 54 + j] * w;
        a2 += hs[2 * 54 + j] * w;
        a3 += hs[3 * 54 + j] * w;
    }
    float bo = bout[a];
    out[(size_t)(b0 + 0) * N_NODE + a] = a0 + bo;
    out[(size_t)(b0 + 1) * N_NODE + a] = a1 + bo;
    out[(size_t)(b0 + 2) * N_NODE + a] = a2 + bo;
    out[(size_t)(b0 + 3) * N_NODE + a] = a3 + bo;
}

extern "C" void kernel_launch(void* const* d_in, const int* in_sizes, int n_in,
                              void* d_out, int out_size, void* d_ws, size_t ws_size,
                              hipStream_t stream) {
    const float* X    = (const float*)d_in[0];
    const float* adj  = (const float*)d_in[1];
    const float* W1   = (const float*)d_in[2];
    const float* b1   = (const float*)d_in[3];
    const float* W2   = (const float*)d_in[4];
    const float* b2   = (const float*)d_in[5];
    const float* W3   = (const float*)d_in[6];
    const float* b3   = (const float*)d_in[7];
    const float* Wfc  = (const float*)d_in[8];
    const float* bfc  = (const float*)d_in[9];
    const float* Wout = (const float*)d_in[10];
    const float* bout = (const float*)d_in[11];
    float* out = (float*)d_out;

    // ws: adjB (A-pack) 32MB | G0 packed 4MB | H1 packed 4MB | H2g packed 4MB
    //   | hid [128][54]
    char* w = (char*)d_ws;
    __bf16* adjB = (__bf16*)w;
    __bf16* G0   = (__bf16*)(w + 33554432);
    __bf16* H1   = (__bf16*)(w + 33554432 + 4194304);
    __bf16* H2g  = (__bf16*)(w + 33554432 + 2 * 4194304);
    float*  hid  = (float*)(w + 33554432 + 3 * 4194304);

    prep_k<<<9243, 256, 0, stream>>>(adj, adjB, X, W1, G0, hid);

    // stage 1: H1 = relu(adj @ G0 + b1)            (W1 pre-applied in prep)
    gcn_k<0><<<512, 512, 0, stream>>>(adjB, G0, nullptr, b1, nullptr, H1, nullptr);
    // stage 2: H2g = (relu(adj @ H1 @ W2 + b2)) @ W3, padded f=4
    gcn_k<1><<<512, 512, 0, stream>>>(adjB, H1, W2, b2, W3, H2g, nullptr);
    // stage 3: fused  relu(adj @ H2g + b3)  +  fc1 partial sums -> hid
    gcn_k<2><<<512, 512, 0, stream>>>(adjB, H2g, Wfc, b3, nullptr, nullptr, hid);

    // FC head tail
    fc2_k<<<dim3(16, 32), 256, 0, stream>>>(hid, bfc, Wout, bout, out);
}